// Round 5
// baseline (490.582 us; speedup 1.0000x reference)
//
#include <hip/hip_runtime.h>
#include <hip/hip_bf16.h>

#define D 128
#define CAP 64     // max edges per src node (Poisson(16); verified passing on real data)
#define GCAP 192   // max nodes per graph  (Poisson(97.7); verified passing on real data)

typedef __attribute__((ext_vector_type(8))) short short8;
typedef __attribute__((ext_vector_type(4))) float f32x4;

__device__ __forceinline__ float b2f(unsigned short u) {
    union { unsigned int i; float f; } v;
    v.i = ((unsigned int)u) << 16;
    return v.f;
}
__device__ __forceinline__ unsigned short f2b(float f) {
    __hip_bfloat16 h = __float2bfloat16(f);   // RNE
    return __builtin_bit_cast(unsigned short, h);
}

// ---------------------------------------------------------------------------
// Both weight transposes + hi/lo bf16 splits in one kernel.
// blocks 0..63 -> W_in, 64..127 -> W_gcn.
__global__ void k_prep(const float* __restrict__ Wa, unsigned short* __restrict__ Ahi,
                       unsigned short* __restrict__ Alo,
                       const float* __restrict__ Wb, unsigned short* __restrict__ Bhi,
                       unsigned short* __restrict__ Blo) {
    int b = blockIdx.x;
    const float* W = (b < 64) ? Wa : Wb;
    unsigned short* Hi = (b < 64) ? Ahi : Bhi;
    unsigned short* Lo = (b < 64) ? Alo : Blo;
    int i = (b & 63) * 256 + threadIdx.x;     // 64 blocks * 256 = 16384
    int k = i >> 7, n = i & 127;
    float w = W[i];
    unsigned short hi = f2b(w);
    unsigned short lo = f2b(w - b2f(hi));
    Hi[n * D + k] = hi;
    Lo[n * D + k] = lo;
}

// ---------------------------------------------------------------------------
// Mega kernel: blocks [0, gemmBlocks) run the fused double-GEMM
// (hw = relu(x@W_in+b_in) @ W_gcn, bf16 out); blocks [gemmBlocks, ...) run
// the CSR bucket build with 4 independent atomic->store chains per thread
// (latency-bound op: ILP-4 quarters the serialized round-trips).
// The two halves are independent; co-resident waves hide each other
// (build waits on fabric while GEMM uses MFMA/VALU).
__global__ __launch_bounds__(256) void k_mega(
        // gemm args
        const float* __restrict__ X,
        const unsigned short* __restrict__ W1hi, const unsigned short* __restrict__ W1lo,
        const float* __restrict__ bias1,
        const unsigned short* __restrict__ W2hi, const unsigned short* __restrict__ W2lo,
        unsigned short* __restrict__ HW, int N,
        // build args
        const int* __restrict__ esrc, const int* __restrict__ edst,
        const float* __restrict__ eval,
        int* __restrict__ cnt, int2* __restrict__ edata, int E,
        const int* __restrict__ bids, const float* __restrict__ bval,
        int* __restrict__ gcnt, int2* __restrict__ gdata,
        int gemmBlocks, int graphBuildBlocks) {
    __shared__ float lds[4 * 16 * 132];               // stride 132: 2-way max (free)

    if (blockIdx.x >= (unsigned)gemmBlocks) {
        // ---------------- build branch ----------------
        int b = blockIdx.x - gemmBlocks;
        int base = b * 1024 + threadIdx.x;
#pragma unroll
        for (int u = 0; u < 4; u++) {                 // 4 independent chains
            int e = base + u * 256;
            if (e < E) {
                int s = esrc[e];
                int slot = atomicAdd(&cnt[s], 1);
                if (slot < CAP) {
                    int2 d; d.x = edst[e]; d.y = __float_as_int(eval[e]);
                    edata[(size_t)s * CAP + slot] = d;
                }
            }
        }
        if (b < graphBuildBlocks) {
#pragma unroll
            for (int u = 0; u < 4; u++) {
                int i = base + u * 256;
                if (i < N) {
                    int g = bids[i];
                    int slot = atomicAdd(&gcnt[g], 1);
                    if (slot < GCAP) {
                        int2 d; d.x = i; d.y = __float_as_int(bval[i]);
                        gdata[(size_t)g * GCAP + slot] = d;
                    }
                }
            }
        }
        return;
    }

    // ---------------- fused double-GEMM branch ----------------
    const int wave = threadIdx.x >> 6;
    const int lane = threadIdx.x & 63;
    const int q = lane >> 4;
    const int l15 = lane & 15;
    const int row0 = blockIdx.x * 64 + wave * 16;
    float* tile = lds + wave * 16 * 132;

    int arow = row0 + l15;
    if (arow >= N) arow = N - 1;                      // clamp; stores guarded
    const float* xrow = X + (size_t)arow * D;

    f32x4 acc[8];
#pragma unroll
    for (int t = 0; t < 8; t++) acc[t] = (f32x4){0.f, 0.f, 0.f, 0.f};

    // ---- GEMM 1: acc = x @ W_in (hi/lo split, 3 MFMAs/tile ~ fp32) ----
#pragma unroll
    for (int kk = 0; kk < 4; kk++) {
        float4 f0 = *(const float4*)(xrow + kk * 32 + q * 8);
        float4 f1 = *(const float4*)(xrow + kk * 32 + q * 8 + 4);
        float fv[8] = {f0.x, f0.y, f0.z, f0.w, f1.x, f1.y, f1.z, f1.w};
        short8 ahi, alo;
#pragma unroll
        for (int j = 0; j < 8; j++) {
            unsigned short h = f2b(fv[j]);
            ahi[j] = (short)h;
            alo[j] = (short)f2b(fv[j] - b2f(h));
        }
#pragma unroll
        for (int t = 0; t < 8; t++) {
            size_t woff = (size_t)(t * 16 + l15) * D + kk * 32 + q * 8;
            short8 bhi = *(const short8*)(W1hi + woff);
            short8 blo = *(const short8*)(W1lo + woff);
            acc[t] = __builtin_amdgcn_mfma_f32_16x16x32_bf16(ahi, bhi, acc[t], 0, 0, 0);
            acc[t] = __builtin_amdgcn_mfma_f32_16x16x32_bf16(ahi, blo, acc[t], 0, 0, 0);
            acc[t] = __builtin_amdgcn_mfma_f32_16x16x32_bf16(alo, bhi, acc[t], 0, 0, 0);
        }
    }

    // ---- bias + relu, park h in wave-private LDS (C-layout -> row-major) ----
#pragma unroll
    for (int t = 0; t < 8; t++) {
        int col = t * 16 + l15;
        float bv = bias1[col];
#pragma unroll
        for (int r = 0; r < 4; r++) {
            float v = acc[t][r] + bv;
            v = v > 0.f ? v : 0.f;
            tile[(q * 4 + r) * 132 + col] = v;
        }
    }

    // ---- GEMM 2: acc = h @ W_gcn (read h back in A-layout) ----
#pragma unroll
    for (int t = 0; t < 8; t++) acc[t] = (f32x4){0.f, 0.f, 0.f, 0.f};
#pragma unroll
    for (int kk = 0; kk < 4; kk++) {
        const float* hp = tile + l15 * 132 + kk * 32 + q * 8;
        float4 f0 = *(const float4*)(hp);
        float4 f1 = *(const float4*)(hp + 4);
        float fv[8] = {f0.x, f0.y, f0.z, f0.w, f1.x, f1.y, f1.z, f1.w};
        short8 ahi, alo;
#pragma unroll
        for (int j = 0; j < 8; j++) {
            unsigned short h = f2b(fv[j]);
            ahi[j] = (short)h;
            alo[j] = (short)f2b(fv[j] - b2f(h));
        }
#pragma unroll
        for (int t = 0; t < 8; t++) {
            size_t woff = (size_t)(t * 16 + l15) * D + kk * 32 + q * 8;
            short8 bhi = *(const short8*)(W2hi + woff);
            short8 blo = *(const short8*)(W2lo + woff);
            acc[t] = __builtin_amdgcn_mfma_f32_16x16x32_bf16(ahi, bhi, acc[t], 0, 0, 0);
            acc[t] = __builtin_amdgcn_mfma_f32_16x16x32_bf16(ahi, blo, acc[t], 0, 0, 0);
            acc[t] = __builtin_amdgcn_mfma_f32_16x16x32_bf16(alo, bhi, acc[t], 0, 0, 0);
        }
    }

    // ---- store hw as bf16 ----
#pragma unroll
    for (int t = 0; t < 8; t++) {
        int col = t * 16 + l15;
#pragma unroll
        for (int r = 0; r < 4; r++) {
            int row = row0 + q * 4 + r;
            if (row < N) HW[(size_t)row * D + col] = f2b(acc[t][r]);
        }
    }
}

// ---------------------------------------------------------------------------
// One wave per node: gather its edges' bf16 hw rows (1 uint/lane/edge),
// register-accumulate fp32, relu, l2-normalize, write h_struct. No atomics.
__global__ __launch_bounds__(256) void k_agg_finalize(
        const int* __restrict__ cnt, const int2* __restrict__ edata,
        const unsigned int* __restrict__ hw32,   // hw as packed 2xbf16
        float* __restrict__ hstruct, int N) {
    const int lane = threadIdx.x & 63;
    const int node = blockIdx.x * 4 + (threadIdx.x >> 6);
    if (node >= N) return;
    int deg = cnt[node];
    if (deg > CAP) deg = CAP;

    int myDst = 0; float myVal = 0.f;
    if (lane < deg) {
        int2 ed = edata[(size_t)node * CAP + lane];
        myDst = ed.x; myVal = __int_as_float(ed.y);
    }

    float a0 = 0.f, a1 = 0.f;
#pragma unroll 4
    for (int j = 0; j < deg; j++) {
        int dj = __shfl(myDst, j, 64);
        float vj = __shfl(myVal, j, 64);
        unsigned int p = hw32[(size_t)dj * 64 + lane];
        a0 = fmaf(vj, b2f((unsigned short)(p & 0xffffu)), a0);
        a1 = fmaf(vj, b2f((unsigned short)(p >> 16)), a1);
    }

    a0 = a0 > 0.f ? a0 : 0.f;
    a1 = a1 > 0.f ? a1 : 0.f;
    float ss = a0 * a0 + a1 * a1;
#pragma unroll
    for (int m = 1; m < 64; m <<= 1) ss += __shfl_xor(ss, m, 64);
    float scale = 1.0f / fmaxf(sqrtf(ss), 1e-12f);
    float2 o; o.x = a0 * scale; o.y = a1 * scale;
    *(float2*)(hstruct + (size_t)node * D + 2 * lane) = o;
}

// ---------------------------------------------------------------------------
// One wave per graph: weighted-gather h_struct rows, then
// l2norm(relu(hg @ W_g + b_g)) via shfl-broadcast dot.
__global__ __launch_bounds__(256) void k_graph_finalize(
        const int* __restrict__ gcnt, const int2* __restrict__ gdata,
        const float* __restrict__ hstruct,
        const float* __restrict__ Wg, const float* __restrict__ bg,
        float* __restrict__ out, int G) {
    const int lane = threadIdx.x & 63;
    const int g = blockIdx.x * 4 + (threadIdx.x >> 6);
    if (g >= G) return;
    int deg = gcnt[g];
    if (deg > GCAP) deg = GCAP;
    const int c0 = 2 * lane;

    float a0 = 0.f, a1 = 0.f;   // hg[g][c0], hg[g][c0+1]
    for (int base = 0; base < deg; base += 64) {
        int nrem = deg - base; if (nrem > 64) nrem = 64;
        int myNode = 0; float myW = 0.f;
        if (lane < nrem) {
            int2 ed = gdata[(size_t)g * GCAP + base + lane];
            myNode = ed.x; myW = __int_as_float(ed.y);
        }
#pragma unroll 4
        for (int j = 0; j < nrem; j++) {
            int nj = __shfl(myNode, j, 64);
            float wj = __shfl(myW, j, 64);
            float2 hs = *(const float2*)(hstruct + (size_t)nj * D + c0);
            a0 = fmaf(wj, hs.x, a0);
            a1 = fmaf(wj, hs.y, a1);
        }
    }

    float o0 = 0.f, o1 = 0.f;
#pragma unroll 2
    for (int k = 0; k < D; k++) {
        float xv = (k & 1) ? __shfl(a1, k >> 1, 64) : __shfl(a0, k >> 1, 64);
        float2 w = *(const float2*)(Wg + (size_t)k * D + c0);
        o0 = fmaf(xv, w.x, o0);
        o1 = fmaf(xv, w.y, o1);
    }
    o0 += bg[c0];
    o1 += bg[c0 + 1];
    o0 = o0 > 0.f ? o0 : 0.f;
    o1 = o1 > 0.f ? o1 : 0.f;
    float ss = o0 * o0 + o1 * o1;
#pragma unroll
    for (int m = 1; m < 64; m <<= 1) ss += __shfl_xor(ss, m, 64);
    float scale = 1.0f / fmaxf(sqrtf(ss), 1e-12f);
    float2 o; o.x = o0 * scale; o.y = o1 * scale;
    *(float2*)(out + (size_t)g * D + c0) = o;
}

// ---------------------------------------------------------------------------
extern "C" void kernel_launch(void* const* d_in, const int* in_sizes, int n_in,
                              void* d_out, int out_size, void* d_ws, size_t ws_size,
                              hipStream_t stream) {
    const float* x     = (const float*)d_in[0];
    const int*   esrc  = (const int*)d_in[1];
    const int*   edst  = (const int*)d_in[2];
    const float* eval  = (const float*)d_in[3];
    const int*   bids  = (const int*)d_in[4];
    const float* bval  = (const float*)d_in[5];
    const float* W_in  = (const float*)d_in[6];
    const float* b_in  = (const float*)d_in[7];
    const float* W_gcn = (const float*)d_in[8];
    const float* W_g   = (const float*)d_in[9];
    const float* b_g   = (const float*)d_in[10];

    const int N = in_sizes[4];      // batch_ids length = num nodes
    const int E = in_sizes[1];      // edge_src length
    const int G = 1024;             // num_graphs (problem constant)

    char* ws = (char*)d_ws;
    unsigned short* whi_in  = (unsigned short*)ws; ws += (size_t)D * D * 2;
    unsigned short* wlo_in  = (unsigned short*)ws; ws += (size_t)D * D * 2;
    unsigned short* whi_gcn = (unsigned short*)ws; ws += (size_t)D * D * 2;
    unsigned short* wlo_gcn = (unsigned short*)ws; ws += (size_t)D * D * 2;
    int*   cnt   = (int*)ws;   ws += (size_t)N * 4;          // node edge counters
    int*   gcnt  = (int*)ws;   ws += (size_t)G * 4;          // graph node counters
    unsigned short* hw = (unsigned short*)ws; ws += (size_t)N * D * 2;  // hw, bf16
    int2*  edata = (int2*)ws;  ws += (size_t)N * CAP * 8;    // {dst, val} per src
    int2*  gdata = (int2*)ws;  ws += (size_t)G * GCAP * 8;   // {node, bval} per graph

    hipMemsetAsync(cnt, 0, (size_t)(N + G) * 4, stream);     // cnt+gcnt contiguous

    k_prep<<<128, 256, 0, stream>>>(W_in, whi_in, wlo_in, W_gcn, whi_gcn, wlo_gcn);

    const int gemmBlocks  = (N + 63) / 64;                   // 1563
    const int buildBlocks = (E + 1023) / 1024;               // 1563 (ILP-4, 256 thr)
    const int graphBuildBlocks = (N + 1023) / 1024;          // 98
    k_mega<<<gemmBlocks + buildBlocks, 256, 0, stream>>>(
        x, whi_in, wlo_in, b_in, whi_gcn, wlo_gcn, hw, N,
        esrc, edst, eval, cnt, edata, E,
        bids, bval, gcnt, gdata,
        gemmBlocks, graphBuildBlocks);

    float* hstruct = (float*)d_out;
    float* hgraph  = hstruct + (size_t)N * D;

    k_agg_finalize<<<(N + 3) / 4, 256, 0, stream>>>(cnt, edata,
                                                    (const unsigned int*)hw, hstruct, N);
    k_graph_finalize<<<(G + 3) / 4, 256, 0, stream>>>(gcnt, gdata, hstruct, W_g, b_g, hgraph, G);
}